// Round 5
// baseline (187.895 us; speedup 1.0000x reference)
//
#include <hip/hip_runtime.h>
#include <cstdint>

// ECT loss, exact elementwise formulation (absmax 0.0 across R1/R3/R4).
// A[bc][r][d] = sum_p dw[b,p,c] * sigmoid(8*(lin_r - <x_p, v_d>)), c in {0,1};
// c2 = -(c0+c1); loss = mean over 12288.
//
// R5: R4's barrier-free (d, rg) accumulate loop, but 1024-thread blocks
// (4 teams x 256) so the CU holds 32 waves (8/SIMD) — R4 measured 15% occupancy
// and VALUBusy 35% (latency-bound at 2 waves/SIMD). Teams split the block's
// 216 voxels 54 each; one LDS reduction merges teams; 8192 global atomics
// per block into 4 replicas (same 64 MB write traffic as R4).
//
// ws: gacc[4][8192] floats = 128 KB. gacc layout: rep*8192 + bc*2048 + r*32 + d.

#define P_TOT 110592
#define VOX 216
#define TVOX 54
#define NREP 4

__device__ __forceinline__ uint32_t rotl32(uint32_t x, int d) {
  return (x << d) | (x >> (32 - d));
}

// threefry2x32, key = (0,17) — bit-exact vs jax (verified R1-R4)
__device__ __forceinline__ void threefry_0_17(uint32_t x0, uint32_t x1,
                                              uint32_t& o0, uint32_t& o1) {
  const uint32_t ks0 = 0u, ks1 = 17u, ks2 = 0x1BD11BDAu ^ 0u ^ 17u;
  x0 += ks0; x1 += ks1;
#define R4(a,b,c,dd) \
  x0 += x1; x1 = rotl32(x1,(a)); x1 ^= x0; \
  x0 += x1; x1 = rotl32(x1,(b)); x1 ^= x0; \
  x0 += x1; x1 = rotl32(x1,(c)); x1 ^= x0; \
  x0 += x1; x1 = rotl32(x1,(dd)); x1 ^= x0;
  R4(13,15,26,6)   x0 += ks1; x1 += ks2 + 1u;
  R4(17,29,16,24)  x0 += ks2; x1 += ks0 + 2u;
  R4(13,15,26,6)   x0 += ks0; x1 += ks1 + 3u;
  R4(17,29,16,24)  x0 += ks1; x1 += ks2 + 4u;
  R4(13,15,26,6)   x0 += ks2; x1 += ks0 + 5u;
#undef R4
  o0 = x0; o1 = x1;
}

// XLA ErfInv32 — bit-exact vs jax (verified R1-R4)
__device__ __forceinline__ float erfinv_f32(float x) {
  float w = -log1pf(-x * x);
  float p;
  if (w < 5.0f) {
    w = w - 2.5f;
    p = 2.81022636e-08f;
    p = fmaf(p, w, 3.43273939e-07f);
    p = fmaf(p, w, -3.5233877e-06f);
    p = fmaf(p, w, -4.39150654e-06f);
    p = fmaf(p, w, 0.00021858087f);
    p = fmaf(p, w, -0.00125372503f);
    p = fmaf(p, w, -0.00417768164f);
    p = fmaf(p, w, 0.246640727f);
    p = fmaf(p, w, 1.50140941f);
  } else {
    w = sqrtf(w) - 3.0f;
    p = -0.000200214257f;
    p = fmaf(p, w, 0.000100950558f);
    p = fmaf(p, w, 0.00134934322f);
    p = fmaf(p, w, 0.000337081863f);
    p = fmaf(p, w, 0.00573950773f);
    p = fmaf(p, w, -0.0076224613f);
    p = fmaf(p, w, 0.00943887047f);
    p = fmaf(p, w, 1.00167406f);
    p = fmaf(p, w, 2.83297682f);
  }
  return p * x;
}

__global__ __launch_bounds__(1024, 8) void ect_main(
    const float* __restrict__ pred, const int* __restrict__ tgt,
    float* __restrict__ gacc) {
  __shared__ float dirs[96];        // [3][32] unit directions
  __shared__ float4 voxdw[VOX];     // (b0c0,b0c1,b1c0,b1c1)
  __shared__ float4 voxc[VOX];      // (cx,cy,cz,-)
  __shared__ float accred[8192];    // bc*2048 + r*32 + d

  const int t = threadIdx.x;
  const int bx = blockIdx.x;
  const int team = t >> 8;
  const int local = t & 255;
  const int d = local & 31;
  const int rg = local >> 5;
  const int cbase = bx * VOX;

  // ---- init: directions ----
  if (t < 96) {
    uint32_t o0, o1;
    threefry_0_17(0u, (uint32_t)t, o0, o1);
    uint32_t bits = o0 ^ o1;
    float u = __uint_as_float((bits >> 9) | 0x3F800000u) - 1.0f;
    const float lo = -0.99999994f;
    float v = fmaf(u, 2.0f, lo);
    v = fmaxf(v, lo);
    dirs[t] = 1.41421356237f * erfinv_f32(v);
  }
  __syncthreads();
  if (t < 32) {
    float a = dirs[t], b = dirs[32 + t], c = dirs[64 + t];
    float n = fmaxf(sqrtf(a * a + b * b + c * c), 1e-12f);
    dirs[t] = a / n; dirs[32 + t] = b / n; dirs[64 + t] = c / n;
  }
  // ---- init: per-voxel dw (softmax - onehot) and coords ----
  if (t < VOX) {
    int p = cbase + t;
    int ix = p / 2304; int rem = p - ix * 2304;
    int iy = rem / 48; int iz = rem - iy * 48;
    const float delta = 2.0f / 47.0f;
    voxc[t] = float4{(float)ix * delta - 1.0f, (float)iy * delta - 1.0f,
                     (float)iz * delta - 1.0f, 0.0f};
    float w[4];
#pragma unroll
    for (int b = 0; b < 2; b++) {
      const float* pb = pred + b * (3 * P_TOT) + p;
      float x0 = pb[0], x1 = pb[P_TOT], x2 = pb[2 * P_TOT];
      float m = fmaxf(x0, fmaxf(x1, x2));
      float e0 = __expf(x0 - m), e1 = __expf(x1 - m), e2 = __expf(x2 - m);
      float inv = 1.0f / (e0 + e1 + e2);
      int tg = tgt[b * P_TOT + p];
      w[b * 2 + 0] = e0 * inv - ((tg == 0) ? 1.0f : 0.0f);
      w[b * 2 + 1] = e1 * inv - ((tg == 1) ? 1.0f : 0.0f);
    }
    voxdw[t] = float4{w[0], w[1], w[2], w[3]};
  }
  // zero the reduction buffer while we're pre-barrier
  for (int i = t; i < 8192; i += 1024) accred[i] = 0.0f;
  __syncthreads();

  // per-thread constants
  const float dir0 = dirs[d], dir1 = dirs[32 + d], dir2 = dirs[64 + d];
  const float radius = 1.1f * 1.7320508075688772f;
  const float step = (2.0f * radius) / 63.0f;
  float K[8];
#pragma unroll
  for (int j = 0; j < 8; j++) {
    float lin = fmaf((float)(rg * 8 + j), step, -radius);
    K[j] = __expf(-8.0f * lin);
  }

  float acc[8][4];
#pragma unroll
  for (int j = 0; j < 8; j++)
#pragma unroll
    for (int bc = 0; bc < 4; bc++) acc[j][bc] = 0.0f;

  // ---- main loop: barrier-free, 54 voxels per team ----
  const int vbase = team * TVOX;
#pragma unroll 2
  for (int v = vbase; v < vbase + TVOX; v++) {
    float4 c = voxc[v];
    float4 w = voxdw[v];
    float nh = fmaf(c.z, dir2, fmaf(c.y, dir1, c.x * dir0));
    float E = __expf(8.0f * nh);              // <= e^13.9, no overflow
    float z[8];
#pragma unroll
    for (int j = 0; j < 8; j++) z[j] = fmaf(E, K[j], 1.0f);  // 1..4.4e12
#pragma unroll
    for (int h = 0; h < 4; h++) {
      // paired reciprocal: product <= 2e25, no overflow
      float pz = z[2 * h] * z[2 * h + 1];
      float rr = __builtin_amdgcn_rcpf(pz);
      float s0 = z[2 * h + 1] * rr;           // sigmoid for r = rg*8+2h
      float s1 = z[2 * h] * rr;               // sigmoid for r = rg*8+2h+1
      acc[2 * h][0] = fmaf(w.x, s0, acc[2 * h][0]);
      acc[2 * h][1] = fmaf(w.y, s0, acc[2 * h][1]);
      acc[2 * h][2] = fmaf(w.z, s0, acc[2 * h][2]);
      acc[2 * h][3] = fmaf(w.w, s0, acc[2 * h][3]);
      acc[2 * h + 1][0] = fmaf(w.x, s1, acc[2 * h + 1][0]);
      acc[2 * h + 1][1] = fmaf(w.y, s1, acc[2 * h + 1][1]);
      acc[2 * h + 1][2] = fmaf(w.z, s1, acc[2 * h + 1][2]);
      acc[2 * h + 1][3] = fmaf(w.w, s1, acc[2 * h + 1][3]);
    }
  }

  // ---- merge teams in LDS (conflict-free rows; 4-way team atomics) ----
  __syncthreads();   // ensure accred zeroing visible (done pre-main)
#pragma unroll
  for (int j = 0; j < 8; j++) {
    int row = (rg * 8 + j) * 32 + d;
#pragma unroll
    for (int bc = 0; bc < 4; bc++)
      atomicAdd(&accred[bc * 2048 + row], acc[j][bc]);
  }
  __syncthreads();

  // ---- global merge: 8192 atomics per block into replica bx&3 ----
  float* grep = gacc + (size_t)(bx & (NREP - 1)) * 8192;
  for (int i = t; i < 8192; i += 1024) atomicAdd(&grep[i], accred[i]);
}

__global__ __launch_bounds__(256) void ect_fin(
    const float* __restrict__ gacc, float* __restrict__ out) {
  __shared__ float red[4];
  int t = threadIdx.x;
  float s = 0.0f;
  for (int i = t; i < 2048; i += 256) {       // i = r*32 + d
    float a0 = 0.f, a1 = 0.f, a2 = 0.f, a3 = 0.f;
#pragma unroll
    for (int rep = 0; rep < NREP; rep++) {
      const float* g = gacc + (size_t)rep * 8192;
      a0 += g[i];
      a1 += g[2048 + i];
      a2 += g[4096 + i];
      a3 += g[6144 + i];
    }
    s += a0 * a0 + a1 * a1 + (a0 + a1) * (a0 + a1)
       + a2 * a2 + a3 * a3 + (a2 + a3) * (a2 + a3);
  }
#pragma unroll
  for (int off = 32; off > 0; off >>= 1) s += __shfl_down(s, off, 64);
  if ((t & 63) == 0) red[t >> 6] = s;
  __syncthreads();
  if (t == 0) out[0] = (red[0] + red[1] + red[2] + red[3]) * (1.0f / 12288.0f);
}

extern "C" void kernel_launch(void* const* d_in, const int* in_sizes, int n_in,
                              void* d_out, int out_size, void* d_ws, size_t ws_size,
                              hipStream_t stream) {
  const float* pred = (const float*)d_in[0];
  const int* tgt = (const int*)d_in[1];
  float* gacc = (float*)d_ws;                  // 4 * 8192 floats = 128 KB
  float* out = (float*)d_out;

  hipMemsetAsync(gacc, 0, (size_t)NREP * 8192 * sizeof(float), stream);
  hipLaunchKernelGGL(ect_main, dim3(512), dim3(1024), 0, stream, pred, tgt, gacc);
  hipLaunchKernelGGL(ect_fin, dim3(1), dim3(256), 0, stream, gacc, out);
}